// Round 4
// baseline (72.105 us; speedup 1.0000x reference)
//
#include <hip/hip_runtime.h>
#include <hip/hip_bf16.h>
#include <math.h>

#define Bsz 16
#define Nn  500
#define Deg 32
#define Hd  128
#define Pg  100
#define Etot 16000   // Nn*Deg
#define CHUNKS 64
#define ROWS_PER_CHUNK 250  // Etot / CHUNKS
#define NB_PREP 256
#define NB_MEAN (Bsz * CHUNKS)   // 1024
#define NB_OG   (Bsz * Pg)       // 1600

// ============ K1: weight prep + mean partials + og gather/copy + nk ============
// blocks [0,256): MT/AT/BT/GT prep
// blocks [256,1280): per-(b,chunk) mean partials
// blocks [1280,2880): per-bp outgoing-embedding copy + node_keys
__global__ __launch_bounds__(256) void mega1(const float* __restrict__ emb,
                                             const float* __restrict__ wq,
                                             const float* __restrict__ wk,
                                             const float* __restrict__ wql,
                                             const float* __restrict__ wqv,
                                             const float* __restrict__ wqg,
                                             const int* __restrict__ indices,
                                             const int* __restrict__ lni_arr,
                                             float* __restrict__ partial,
                                             float* __restrict__ mt,
                                             float* __restrict__ at,
                                             float* __restrict__ bt,
                                             float* __restrict__ gt,
                                             float* __restrict__ out_nk,
                                             float* __restrict__ out_og) {
    int blk = blockIdx.x;
    int tid = threadIdx.x;

    if (blk >= NB_PREP + NB_MEAN) {
        // ---- og copy + nk ----
        int bp = blk - (NB_PREP + NB_MEAN);
        int b = bp / Pg;
        int lni = lni_arr[bp];
        if (tid < Deg) {
            int nk = indices[(((size_t)b * Etot) + (size_t)lni * Deg + tid) * 2 + 1];
            out_nk[(size_t)bp * Deg + tid] = (float)nk;
        }
        const float4* ebase = (const float4*)(emb) + ((size_t)b * Etot + (size_t)lni * Deg) * 32;
        float4* obase = (float4*)(out_og) + (size_t)bp * Deg * 32;
        int grp = tid >> 5, c4 = tid & 31;
#pragma unroll
        for (int r = 0; r < 4; ++r) {
            int rr = grp + r * 8;
            obase[rr * 32 + c4] = ebase[rr * 32 + c4];
        }
        return;
    }

    __shared__ float4 red[256];
    __shared__ float wv_s[2][Hd];

    if (blk >= NB_PREP) {
        // ---- mean partials ----
        int mb = blk - NB_PREP;
        int b = mb >> 6, chunk = mb & 63;
        int rgrp = tid >> 5, c4 = tid & 31;
        const float4* base = (const float4*)(emb + (size_t)b * Etot * Hd);
        int e0 = chunk * ROWS_PER_CHUNK;
        float4 acc = make_float4(0.f, 0.f, 0.f, 0.f);
        for (int e = e0 + rgrp; e < e0 + ROWS_PER_CHUNK; e += 8) {
            float4 v = base[(size_t)e * 32 + c4];
            acc.x += v.x; acc.y += v.y; acc.z += v.z; acc.w += v.w;
        }
        red[tid] = acc;
        __syncthreads();
        for (int s = 128; s >= 32; s >>= 1) {
            if (tid < s) {
                float4 a = red[tid], o = red[tid + s];
                a.x += o.x; a.y += o.y; a.z += o.z; a.w += o.w;
                red[tid] = a;
            }
            __syncthreads();
        }
        if (tid < 32)
            ((float4*)partial)[((size_t)b * CHUNKS + chunk) * 32 + tid] = red[tid];
        return;
    }

    // ---- weight prep ----
    int h = tid >> 7;
    int r = tid & 127;
    if (blk < 64) {
        int s = (blk << 1) | h;
        float acc = 0.f;
#pragma unroll 8
        for (int t = 0; t < Hd; ++t)
            acc += wq[t * Hd + s] * wk[t * Hd + r];
        mt[s * Hd + r] = acc;
        return;
    }
    int f = (blk - 64) >> 6;                 // 0=AT 1=BT 2=GT
    int u = (((blk - 64) & 63) << 1) | h;
    int t = r;
    float acc1 = 0.f;
    if (f == 0) {
#pragma unroll 8
        for (int s = 0; s < Hd; ++s)
            acc1 += (wql[s * Hd + u] + wqv[s * Hd + u] * (1.f / (float)Nn)) * wq[t * Hd + s];
    } else if (f == 1) {
#pragma unroll 8
        for (int s = 0; s < Hd; ++s)
            acc1 += wqv[s * Hd + u] * wq[t * Hd + s];
    } else {
#pragma unroll 8
        for (int s = 0; s < Hd; ++s)
            acc1 += wqg[s * Hd + u] * wq[t * Hd + s];
    }
    wv_s[h][t] = acc1;
    __syncthreads();
    float acc = 0.f;
#pragma unroll 8
    for (int tt = 0; tt < Hd; ++tt)
        acc += wv_s[h][tt] * wk[tt * Hd + r];
    float* dst = (f == 0) ? at : (f == 1) ? bt : gt;
    dst[u * Hd + r] = acc;
}

// ============ K2: zgemm (into LDS) + score + softmax, 8 bps per block ============
__global__ __launch_bounds__(256) void zscore(const float* __restrict__ partial,
                                              const float* __restrict__ gt,
                                              const float* __restrict__ at,
                                              const float* __restrict__ bt,
                                              const float* __restrict__ mt,
                                              const float* __restrict__ qf,
                                              const float* __restrict__ vis,
                                              const float* __restrict__ le,
                                              const float* __restrict__ dists,
                                              const float* __restrict__ pref,
                                              const int* __restrict__ indices,
                                              const int* __restrict__ lni_arr,
                                              const float* __restrict__ gmask,
                                              const float* __restrict__ out_og,
                                              float* __restrict__ out_probs) {
    int b = blockIdx.x / 13, pblk = blockIdx.x % 13;
    int p0 = pblk * 8, nrows = (pblk == 12) ? 4 : 8;
    int tid = threadIdx.x;

    __shared__ int lni_s[8];
    __shared__ __align__(16) float mean_s[Hd];
    __shared__ __align__(16) float gz_s[Hd];
    __shared__ float ps[2][Hd];
    __shared__ float4 in_s[3][8][32];
    __shared__ __align__(16) float z_s[8][Hd];
    __shared__ float score_s[8][Deg];

    if (tid < nrows) lni_s[tid] = lni_arr[b * Pg + p0 + tid];
    __syncthreads();

    // Prefetch scattered loads into registers (fly under the GEMM phase)
    int bp_i = tid >> 5, d = tid & 31;
    int nk = 0; float2 dd = make_float2(0.f, 0.f); float mval = 0.f;
    if (bp_i < nrows) {
        int lnv = lni_s[bp_i];
        nk = indices[(((size_t)b * Etot) + (size_t)lnv * Deg + d) * 2 + 1];
        dd = *(const float2*)(dists + (((size_t)b * Nn + (size_t)lnv) * Nn + nk) * 2);
        mval = gmask[((size_t)(b * Pg + p0 + bp_i)) * Nn + nk];
    }
    float p0v = pref[0], p1v = pref[1];

    // ---- Phase A: mean reduce + gz + Z GEMM into LDS ----
    {
        int c = tid & 127, h = tid >> 7;
        float s = 0.f;
        const float* pb = partial + (size_t)b * CHUNKS * Hd;
        for (int k = h * 32; k < h * 32 + 32; ++k)
            s += pb[k * Hd + c];
        ps[h][c] = s;
    }
    __syncthreads();
    if (tid < Hd)
        mean_s[tid] = (ps[0][tid] + ps[1][tid]) * (1.f / (float)Etot);
    __syncthreads();
    if (tid < Hd) {
        float g = 0.f;
#pragma unroll 8
        for (int c = 0; c < Hd; ++c)
            g += mean_s[c] * gt[c * Hd + tid];
        gz_s[tid] = g;
    } else {
        int t2 = tid - 128;
        size_t base4 = ((size_t)b * Pg + p0) * 32;
        const float4* le4 = (const float4*)le + base4;
        const float4* vi4 = (const float4*)vis + base4;
        const float4* qf4 = (const float4*)qf + base4;
        int tot = nrows * 32;
        for (int i = t2; i < tot; i += 128) {
            int rr = i >> 5, c4 = i & 31;
            in_s[0][rr][c4] = le4[i];
            in_s[1][rr][c4] = vi4[i];
            in_s[2][rr][c4] = qf4[i];
        }
    }
    __syncthreads();
    {
        int tg = tid & 31, rg = tid >> 5;
        if (rg < nrows) {
            float4 acc = ((const float4*)gz_s)[tg];
            const float4* at4 = (const float4*)at;
            const float4* bt4 = (const float4*)bt;
            const float4* mt4 = (const float4*)mt;
            for (int c4 = 0; c4 < 32; ++c4) {
                float4 lv = in_s[0][rg][c4];
                float4 vv = in_s[1][rg][c4];
                float4 qv = in_s[2][rg][c4];
                int cb = c4 * 4;
#pragma unroll
                for (int j = 0; j < 4; ++j) {
                    float4 wa = at4[(cb + j) * 32 + tg];
                    float4 wb = bt4[(cb + j) * 32 + tg];
                    float4 wm = mt4[(cb + j) * 32 + tg];
                    float lj = j == 0 ? lv.x : j == 1 ? lv.y : j == 2 ? lv.z : lv.w;
                    float vj = j == 0 ? vv.x : j == 1 ? vv.y : j == 2 ? vv.z : vv.w;
                    float qj = j == 0 ? qv.x : j == 1 ? qv.y : j == 2 ? qv.z : qv.w;
                    acc.x += lj * wa.x + vj * wb.x + qj * wm.x;
                    acc.y += lj * wa.y + vj * wb.y + qj * wm.y;
                    acc.z += lj * wa.z + vj * wb.z + qj * wm.z;
                    acc.w += lj * wa.w + vj * wb.w + qj * wm.w;
                }
            }
            ((float4*)z_s[rg])[tg] = acc;
        }
    }
    __syncthreads();

    // ---- Phase B: per-bp og-tile dot z ----
    {
        int rg = tid >> 5, c4 = tid & 31;
        const float4* ogb = (const float4*)out_og + ((size_t)(b * Pg + p0)) * Deg * 32;
        for (int bi = 0; bi < nrows; ++bi) {
            float4 z4 = ((const float4*)z_s[bi])[c4];
#pragma unroll
            for (int r0 = 0; r0 < 4; ++r0) {
                int r = rg + r0 * 8;
                float4 v = ogb[(size_t)bi * 1024 + r * 32 + c4];
                float part = v.x * z4.x + v.y * z4.y + v.z * z4.z + v.w * z4.w;
                for (int m = 16; m >= 1; m >>= 1)
                    part += __shfl_xor(part, m, 64);
                if (c4 == 0) score_s[bi][r] = part;
            }
        }
    }
    __syncthreads();

    // ---- Phase C: softmax over Deg for each of the 8 bps (256 threads = 8x32) ----
    if (bp_i < nrows) {
        float s = score_s[bp_i][d] * 0.011048543456039805f;  // 1/(8*sqrt(128))
        float ds = p0v * dd.x + p1v * dd.y;
        s -= ds * 0.7071067811865476f;                       // /sqrt(2)
        float sc = 10.0f * tanhf(s);
        float m = mval;
        if (isinf(m) && m < 0.f) m = -1.0e8f;
        float v = sc + m;
        float mx = v;
        for (int mm = 16; mm >= 1; mm >>= 1)
            mx = fmaxf(mx, __shfl_xor(mx, mm, 64));
        float e = expf(v - mx);
        float sum = e;
        for (int mm = 16; mm >= 1; mm >>= 1)
            sum += __shfl_xor(sum, mm, 64);
        out_probs[((size_t)(b * Pg + p0 + bp_i)) * Deg + d] = e / sum;
    }
}

extern "C" void kernel_launch(void* const* d_in, const int* in_sizes, int n_in,
                              void* d_out, int out_size, void* d_ws, size_t ws_size,
                              hipStream_t stream) {
    const float* emb       = (const float*)d_in[0];
    const float* dists     = (const float*)d_in[1];
    const float* pref      = (const float*)d_in[2];
    const int*   indices   = (const int*)d_in[3];
    // d_in[4] = Wq_first : unused by the reference
    const float* Wq_last    = (const float*)d_in[5];
    const float* Wq_visited = (const float*)d_in[6];
    const float* Wq_graph   = (const float*)d_in[7];
    const float* Wq         = (const float*)d_in[8];
    const float* Wk         = (const float*)d_in[9];
    const float* q_first    = (const float*)d_in[10];
    const float* visited    = (const float*)d_in[11];
    const float* last_edge  = (const float*)d_in[12];
    const int*   lni        = (const int*)d_in[13];
    const float* gmask      = (const float*)d_in[14];

    float* w = (float*)d_ws;
    float* ws_partial = w;                                       // 16*64*128
    float* ws_mt      = ws_partial + (size_t)Bsz * CHUNKS * Hd;
    float* ws_at      = ws_mt + Hd * Hd;
    float* ws_bt      = ws_at + Hd * Hd;
    float* ws_gt      = ws_bt + Hd * Hd;

    float* out       = (float*)d_out;
    float* out_probs = out;
    float* out_nk    = out + (size_t)Bsz * Pg * Deg;
    float* out_og    = out + 2 * (size_t)Bsz * Pg * Deg;

    mega1<<<NB_PREP + NB_MEAN + NB_OG, 256, 0, stream>>>(emb, Wq, Wk, Wq_last, Wq_visited,
                                                         Wq_graph, indices, lni, ws_partial,
                                                         ws_mt, ws_at, ws_bt, ws_gt,
                                                         out_nk, out_og);
    zscore<<<Bsz * 13, 256, 0, stream>>>(ws_partial, ws_gt, ws_at, ws_bt, ws_mt,
                                         q_first, visited, last_edge, dists, pref,
                                         indices, lni, gmask, out_og, out_probs);
}

// Round 5
// 48.537 us; speedup vs baseline: 1.4856x; 1.4856x over previous
//
#include <hip/hip_runtime.h>
#include <hip/hip_bf16.h>
#include <math.h>

#define Bsz 16
#define Nn  500
#define Deg 32
#define Hd  128
#define Pg  100
#define Etot 16000   // Nn*Deg
#define CHUNKS 64
#define ROWS_PER_CHUNK 250  // Etot / CHUNKS
#define PREP_BLKS 256       // 64 MT + 64 AT + 64 BT + 64 GT

// ============ K1: all weight prep (blocks 0..255) + mean partials (256..1279) ============
// (byte-identical to R3's proven fused_all)
// MT[s*128+r] = sum_t Wq[t,s]*Wk[t,r]
// AT[u*128+r] = sum_t (sum_s CombL[s,u]*Wq[t,s]) * Wk[t,r],  CombL = WqL + WqV/500
// BT[u*128+r] = same with WqV ;  GT[c*128+r] = same with WqG
__global__ __launch_bounds__(256) void fused_all(const float* __restrict__ emb,
                                                 const float* __restrict__ wq,
                                                 const float* __restrict__ wk,
                                                 const float* __restrict__ wql,
                                                 const float* __restrict__ wqv,
                                                 const float* __restrict__ wqg,
                                                 float* __restrict__ partial,
                                                 float* __restrict__ mt,
                                                 float* __restrict__ at,
                                                 float* __restrict__ bt,
                                                 float* __restrict__ gt) {
    int blk = blockIdx.x;
    int tid = threadIdx.x;
    __shared__ float4 red[256];
    __shared__ float wv_s[2][Hd];

    if (blk >= PREP_BLKS) {
        int mb = blk - PREP_BLKS;
        int b = mb >> 6, chunk = mb & 63;
        int rgrp = tid >> 5, c4 = tid & 31;
        const float4* base = (const float4*)(emb + (size_t)b * Etot * Hd);
        int e0 = chunk * ROWS_PER_CHUNK;
        float4 acc = make_float4(0.f, 0.f, 0.f, 0.f);
        for (int e = e0 + rgrp; e < e0 + ROWS_PER_CHUNK; e += 8) {
            float4 v = base[(size_t)e * 32 + c4];
            acc.x += v.x; acc.y += v.y; acc.z += v.z; acc.w += v.w;
        }
        red[tid] = acc;
        __syncthreads();
        for (int s = 128; s >= 32; s >>= 1) {
            if (tid < s) {
                float4 a = red[tid], o = red[tid + s];
                a.x += o.x; a.y += o.y; a.z += o.z; a.w += o.w;
                red[tid] = a;
            }
            __syncthreads();
        }
        if (tid < 32)
            ((float4*)partial)[((size_t)b * CHUNKS + chunk) * 32 + tid] = red[tid];
        return;
    }

    int h = tid >> 7;
    int r = tid & 127;
    if (blk < 64) {
        int s = (blk << 1) | h;
        float acc = 0.f;
#pragma unroll 8
        for (int t = 0; t < Hd; ++t)
            acc += wq[t * Hd + s] * wk[t * Hd + r];
        mt[s * Hd + r] = acc;
        return;
    }
    int f = (blk - 64) >> 6;                 // 0=AT 1=BT 2=GT
    int u = (((blk - 64) & 63) << 1) | h;
    int t = r;
    float acc1 = 0.f;
    if (f == 0) {
#pragma unroll 8
        for (int s = 0; s < Hd; ++s)
            acc1 += (wql[s * Hd + u] + wqv[s * Hd + u] * (1.f / (float)Nn)) * wq[t * Hd + s];
    } else if (f == 1) {
#pragma unroll 8
        for (int s = 0; s < Hd; ++s)
            acc1 += wqv[s * Hd + u] * wq[t * Hd + s];
    } else {
#pragma unroll 8
        for (int s = 0; s < Hd; ++s)
            acc1 += wqg[s * Hd + u] * wq[t * Hd + s];
    }
    wv_s[h][t] = acc1;
    __syncthreads();
    float acc = 0.f;
#pragma unroll 8
    for (int tt = 0; tt < Hd; ++tt)
        acc += wv_s[h][tt] * wk[tt * Hd + r];
    float* dst = (f == 0) ? at : (f == 1) ? bt : gt;
    dst[u * Hd + r] = acc;
}

// ============ K2: per-block z (4 bps) + gather + score + softmax + all outputs ============
// 400 blocks, 4 bps each. z[bp][r] = sum_u AT[u,r]*le[u] + BT[u,r]*vis[u] + MT[u,r]*qf[u]
//                                    + GT[u,r]*mean_b[u]
__global__ __launch_bounds__(256) void decode_z(const float* __restrict__ partial,
                                                const float* __restrict__ gt,
                                                const float* __restrict__ at,
                                                const float* __restrict__ bt,
                                                const float* __restrict__ mt,
                                                const float* __restrict__ qf,
                                                const float* __restrict__ vis,
                                                const float* __restrict__ le,
                                                const float* __restrict__ emb,
                                                const float* __restrict__ dists,
                                                const float* __restrict__ pref,
                                                const int* __restrict__ indices,
                                                const int* __restrict__ lni_arr,
                                                const float* __restrict__ gmask,
                                                float* __restrict__ out_probs,
                                                float* __restrict__ out_nk,
                                                float* __restrict__ out_og) {
    int blk = blockIdx.x;
    int b = blk / 25, p0 = (blk % 25) * 4;
    int bp0 = b * Pg + p0;
    int tid = threadIdx.x;

    __shared__ int lni_s[4];
    __shared__ float ps[2][Hd];
    __shared__ float mean_s[Hd];
    __shared__ __align__(16) float ins[Hd][3][4];   // [u][m][bp]  m: 0=le 1=vis 2=qf
    __shared__ float zpart[2][4][Hd];
    __shared__ __align__(16) float z_s[4][Hd];
    __shared__ float score_s[4][Deg];

    if (tid < 4) lni_s[tid] = lni_arr[bp0 + tid];
    __syncthreads();

    // Prefetch scattered softmax inputs into registers (fly under z-compute + gather)
    int bp_i = tid >> 5, d = tid & 31;
    int nk = 0; float2 dd = make_float2(0.f, 0.f); float mval = 0.f;
    if (tid < 128) {
        int lnv = lni_s[bp_i];
        nk = indices[(((size_t)b * Etot) + (size_t)lnv * Deg + d) * 2 + 1];
        out_nk[(size_t)(bp0 + bp_i) * Deg + d] = (float)nk;
        dd = *(const float2*)(dists + (((size_t)b * Nn + (size_t)lnv) * Nn + nk) * 2);
        mval = gmask[(size_t)(bp0 + bp_i) * Nn + nk];
    }
    float p0v = pref[0], p1v = pref[1];

    // ---- partial-reduce for this b (redundant per block; L2-resident, 32 KB) ----
    {
        int c = tid & 127, h = tid >> 7;
        float s = 0.f;
        const float* pb = partial + (size_t)b * CHUNKS * Hd;
        for (int k = h * 32; k < h * 32 + 32; ++k)
            s += pb[k * Hd + c];
        ps[h][c] = s;
    }
    // ---- stage le/vis/qf for 4 bps into transposed LDS ----
    {
        size_t base4 = (size_t)bp0 * 32;
        const float4* le4 = (const float4*)le + base4;
        const float4* vi4 = (const float4*)vis + base4;
        const float4* qf4 = (const float4*)qf + base4;
        for (int i = tid; i < 384; i += 256) {
            int m = i >> 7, idx = i & 127;
            int bp = idx >> 5, c4 = idx & 31;
            float4 v = (m == 0) ? le4[idx] : (m == 1) ? vi4[idx] : qf4[idx];
            int u0 = c4 * 4;
            ins[u0 + 0][m][bp] = v.x;
            ins[u0 + 1][m][bp] = v.y;
            ins[u0 + 2][m][bp] = v.z;
            ins[u0 + 3][m][bp] = v.w;
        }
    }
    __syncthreads();
    if (tid < Hd)
        mean_s[tid] = (ps[0][tid] + ps[1][tid]) * (1.f / (float)Etot);
    __syncthreads();

    // ---- z for 4 bps: half-split over u ----
    {
        int r = tid & 127, h = tid >> 7;
        float acc0 = 0.f, acc1 = 0.f, acc2 = 0.f, acc3 = 0.f, accg = 0.f;
        const float* atp = at + r;
        const float* btp = bt + r;
        const float* mtp = mt + r;
        const float* gtp = gt + r;
#pragma unroll 4
        for (int u = h * 64; u < h * 64 + 64; ++u) {
            float wa = atp[u * Hd];
            float wb = btp[u * Hd];
            float wm = mtp[u * Hd];
            float wg = gtp[u * Hd];
            accg += wg * mean_s[u];
            float4 lv = *(const float4*)&ins[u][0][0];
            float4 vv = *(const float4*)&ins[u][1][0];
            float4 qv = *(const float4*)&ins[u][2][0];
            acc0 += wa * lv.x + wb * vv.x + wm * qv.x;
            acc1 += wa * lv.y + wb * vv.y + wm * qv.y;
            acc2 += wa * lv.z + wb * vv.z + wm * qv.z;
            acc3 += wa * lv.w + wb * vv.w + wm * qv.w;
        }
        zpart[h][0][r] = acc0 + accg;
        zpart[h][1][r] = acc1 + accg;
        zpart[h][2][r] = acc2 + accg;
        zpart[h][3][r] = acc3 + accg;
    }
    __syncthreads();
    for (int i = tid; i < 512; i += 256) {
        int bp = i >> 7, r = i & 127;
        z_s[bp][r] = zpart[0][bp][r] + zpart[1][bp][r];
    }
    __syncthreads();

    // ---- gather og from emb, copy out, dot with z ----
    {
        int rg = tid >> 5, c4 = tid & 31;
        for (int bp = 0; bp < 4; ++bp) {
            const float4* ebase = (const float4*)emb + ((size_t)b * Etot + (size_t)lni_s[bp] * Deg) * 32;
            float4* ob = (float4*)out_og + ((size_t)(bp0 + bp)) * (Deg * 32);
            float4 z4 = ((const float4*)z_s[bp])[c4];
#pragma unroll
            for (int r0 = 0; r0 < 4; ++r0) {
                int r = rg + r0 * 8;
                float4 v = ebase[r * 32 + c4];
                ob[r * 32 + c4] = v;
                float part = v.x * z4.x + v.y * z4.y + v.z * z4.z + v.w * z4.w;
                for (int m = 16; m >= 1; m >>= 1)
                    part += __shfl_xor(part, m, 64);
                if (c4 == 0) score_s[bp][r] = part;
            }
        }
    }
    __syncthreads();

    // ---- softmax over Deg for the 4 bps (threads 0..127 = 4x32) ----
    if (tid < 128) {
        float s = score_s[bp_i][d] * 0.011048543456039805f;  // 1/(8*sqrt(128))
        float ds = p0v * dd.x + p1v * dd.y;
        s -= ds * 0.7071067811865476f;                       // /sqrt(2)
        float sc = 10.0f * tanhf(s);
        float m = mval;
        if (isinf(m) && m < 0.f) m = -1.0e8f;
        float v = sc + m;
        float mx = v;
        for (int mm = 16; mm >= 1; mm >>= 1)
            mx = fmaxf(mx, __shfl_xor(mx, mm, 64));
        float e = expf(v - mx);
        float sum = e;
        for (int mm = 16; mm >= 1; mm >>= 1)
            sum += __shfl_xor(sum, mm, 64);
        out_probs[(size_t)(bp0 + bp_i) * Deg + d] = e / sum;
    }
}

extern "C" void kernel_launch(void* const* d_in, const int* in_sizes, int n_in,
                              void* d_out, int out_size, void* d_ws, size_t ws_size,
                              hipStream_t stream) {
    const float* emb       = (const float*)d_in[0];
    const float* dists     = (const float*)d_in[1];
    const float* pref      = (const float*)d_in[2];
    const int*   indices   = (const int*)d_in[3];
    // d_in[4] = Wq_first : unused by the reference
    const float* Wq_last    = (const float*)d_in[5];
    const float* Wq_visited = (const float*)d_in[6];
    const float* Wq_graph   = (const float*)d_in[7];
    const float* Wq         = (const float*)d_in[8];
    const float* Wk         = (const float*)d_in[9];
    const float* q_first    = (const float*)d_in[10];
    const float* visited    = (const float*)d_in[11];
    const float* last_edge  = (const float*)d_in[12];
    const int*   lni        = (const int*)d_in[13];
    const float* gmask      = (const float*)d_in[14];

    float* w = (float*)d_ws;
    float* ws_partial = w;                                       // 16*64*128
    float* ws_mt      = ws_partial + (size_t)Bsz * CHUNKS * Hd;
    float* ws_at      = ws_mt + Hd * Hd;
    float* ws_bt      = ws_at + Hd * Hd;
    float* ws_gt      = ws_bt + Hd * Hd;

    float* out       = (float*)d_out;
    float* out_probs = out;
    float* out_nk    = out + (size_t)Bsz * Pg * Deg;
    float* out_og    = out + 2 * (size_t)Bsz * Pg * Deg;

    fused_all<<<PREP_BLKS + Bsz * CHUNKS, 256, 0, stream>>>(emb, Wq, Wk, Wq_last, Wq_visited,
                                                            Wq_graph, ws_partial, ws_mt,
                                                            ws_at, ws_bt, ws_gt);
    decode_z<<<400, 256, 0, stream>>>(ws_partial, ws_gt, ws_at, ws_bt, ws_mt,
                                      q_first, visited, last_edge, emb, dists, pref,
                                      indices, lni, gmask, out_probs, out_nk, out_og);
}